// Round 4
// baseline (705.147 us; speedup 1.0000x reference)
//
#include <hip/hip_runtime.h>

using u16 = unsigned short;
using u32 = unsigned int;
using u64 = unsigned long long;

#define NPTS   16384
#define NPER   8192
#define KNN    16
#define NKROWS (NPTS*KNN)
#define HD     128
#define KCAP   512   // knn per-wave candidate buffer slots
#define NSLOT  16    // fp64 stats partial slots

typedef _Float16 half8 __attribute__((ext_vector_type(8)));
typedef float    floatx4 __attribute__((ext_vector_type(4)));

__device__ __forceinline__ u16  f2h(float f){ _Float16 h=(_Float16)f; return __builtin_bit_cast(u16,h); }
__device__ __forceinline__ float h2f(u16 u){ return (float)__builtin_bit_cast(_Float16,u); }
__device__ __forceinline__ u32 umin32(u32 a,u32 b){ return a<b?a:b; }
__device__ __forceinline__ int cell_of(int x){ return (x*5243)>>17; }   // exact /25 for 0..255

// ---------------------------------------------------------------- grid build
__global__ __launch_bounds__(256) void pack_count(const int* __restrict__ coords, u32* __restrict__ pc,
                                                  u32* __restrict__ cellcnt){
    int i = blockIdx.x*256 + threadIdx.x;
    int x=coords[3*i], y=coords[3*i+1], z=coords[3*i+2];
    pc[i] = (u32)x | ((u32)y<<8) | ((u32)z<<16);
    int cid = ((cell_of(z)*8 + cell_of(y))<<3) + cell_of(x);
    atomicAdd(&cellcnt[(i>>13)*512 + cid], 1u);
}

__global__ __launch_bounds__(1024) void prefix1024(const u32* __restrict__ cellcnt,
                                                   u32* __restrict__ cs, u32* __restrict__ cptr){
    __shared__ u32 tmp[1024];
    int t = threadIdx.x;
    u32 mine = cellcnt[t];
    tmp[t] = mine;
    __syncthreads();
    for (int off=1; off<1024; off<<=1){
        u32 v = (t>=off) ? tmp[t-off] : 0u;
        __syncthreads();
        tmp[t] += v;
        __syncthreads();
    }
    if (t==0) cs[0]=0;
    cs[t+1] = tmp[t];
    cptr[t] = tmp[t] - mine;
}

__global__ __launch_bounds__(256) void scatter_pts(const u32* __restrict__ pc, u32* __restrict__ cptr,
                                                   uint2* __restrict__ spt){
    int i = blockIdx.x*256 + threadIdx.x;
    u32 p = pc[i];
    int cid = ((cell_of((int)((p>>16)&255))*8 + cell_of((int)((p>>8)&255)))<<3) + cell_of((int)(p&255));
    u32 pos = atomicAdd(&cptr[(i>>13)*512 + cid], 1u);
    spt[pos] = make_uint2(p, (u32)(i&8191));
}

// ---------------------------------------------------------------- KNN v4: grid-bucketed, wave-per-query
// grid 4096 x 256; block = 4 waves = 4 queries
__global__ __launch_bounds__(256) void knn_grid(const u32* __restrict__ pc, const uint2* __restrict__ spt,
                                                const u32* __restrict__ cs, int* __restrict__ idx_g,
                                                float* __restrict__ rel, u64* __restrict__ sM){
    __shared__ u32 buf[4][KCAP];
    __shared__ u64 red[9];
    int tid = threadIdx.x;
    int wave = tid>>6, lane = tid&63;
    int scene = blockIdx.x >> 11;
    int q = (blockIdx.x & 2047)*4 + wave;
    if (tid<9) red[tid]=0;
    if (lane<16) buf[wave][lane]=0xFFFFFFFFu;
    __syncthreads();

    u32 qp = pc[scene*NPER + q];
    int qx=(int)(qp&255), qy=(int)((qp>>8)&255), qz=(int)((qp>>16)&255);
    int cx=cell_of(qx), cy=cell_of(qy), cz=cell_of(qz);
    u32 thresh = 0xFFFFFFFFu;
    u32 cnt = 16;

    auto merge = [&](){
        u32 v[8];
#pragma unroll
        for (int r=0;r<8;r++) v[r] = ((u32)(lane + r*64) < cnt) ? buf[wave][lane + r*64] : 0xFFFFFFFFu;
        u32 out = 0;
#pragma unroll
        for (int it=0; it<16; it++){
            u32 m = umin32(umin32(umin32(v[0],v[1]),umin32(v[2],v[3])),
                           umin32(umin32(v[4],v[5]),umin32(v[6],v[7])));
#pragma unroll
            for (int o=32;o>=1;o>>=1) m = umin32(m, (u32)__shfl_xor((int)m, o, 64));
#pragma unroll
            for (int r=0;r<8;r++) if (v[r]==m) v[r]=0xFFFFFFFFu;   // keys unique: at most one clears
            if (lane==it) out = m;
            thresh = m;
        }
        if (lane<16) buf[wave][lane] = out;
        cnt = 16;
    };

    auto scan64 = [&](u32 key){
        u64 mask = __ballot(key < thresh);
        if (mask){
            u32 lt = __builtin_amdgcn_mbcnt_hi((u32)(mask>>32), __builtin_amdgcn_mbcnt_lo((u32)mask,0));
            if (key < thresh) buf[wave][cnt + lt] = key;
            cnt += (u32)__popcll(mask);
            if (cnt > KCAP-64) merge();
        }
    };

    int x0 = cx>0?cx-1:0, x1 = cx<7?cx+1:7;
    int y0 = cy>0?cy-1:0, y1 = cy<7?cy+1:7;
    int z0 = cz>0?cz-1:0, z1 = cz<7?cz+1:7;
    int sbase = scene*512;
    int nx = x1-x0+1;
    for (int rz=z0; rz<=z1; rz++)
        for (int ry=y0; ry<=y1; ry++){
            int c0 = sbase + ((rz*8+ry)<<3) + x0;
            int s = (int)cs[c0], e = (int)cs[c0+nx];
            for (int i=s; i<e; i+=64){
                int p = i + lane;
                u32 key = 0xFFFFFFFFu;
                if (p < e){
                    uint2 pt = spt[p];
                    int dx=(int)(pt.x&255)-qx, dy=(int)((pt.x>>8)&255)-qy, dz=(int)((pt.x>>16)&255)-qz;
                    u32 d2 = (u32)(__mul24(dx,dx)+__mul24(dy,dy)+__mul24(dz,dz));
                    key = (d2<<13) | pt.y;
                }
                scan64(key);
            }
        }
    merge();

    // exactness check: window guarantees radius = min margin to unclipped window faces
    int d2_16 = (int)(thresh>>13);
    int mxl = (cx==0)?1000: qx - 25*(cx-1);
    int mxr = (cx==7)?1000: 25*(cx+2) - qx;
    int myl = (cy==0)?1000: qy - 25*(cy-1);
    int myr = (cy==7)?1000: 25*(cy+2) - qy;
    int mzl = (cz==0)?1000: qz - 25*(cz-1);
    int mzr = (cz==7)?1000: 25*(cz+2) - qz;
    int m = min(min(min(mxl,mxr),min(myl,myr)),min(mzl,mzr));
    if (d2_16 > m*m){                       // rare: exact full-scan fallback
        thresh = 0xFFFFFFFFu; cnt = 16;
        if (lane<16) buf[wave][lane]=0xFFFFFFFFu;
        const u32* sp = pc + scene*NPER;
        for (int t=0;t<128;t++){
            u32 p = sp[t*64+lane];
            int dx=(int)(p&255)-qx, dy=(int)((p>>8)&255)-qy, dz=(int)((p>>16)&255)-qz;
            u32 d2 = (u32)(__mul24(dx,dx)+__mul24(dy,dy)+__mul24(dz,dz));
            scan64((d2<<13) | (u32)(t*64+lane));
        }
        merge();
    }

    // epilogue: emit idx/rel + moment sums (for analytic d1-BN)
    int n = scene*NPER + q;
    u32 key = buf[wave][lane & 15];
    int dx=0,dy=0,dz=0;
    if (lane<16){
        int j = (int)(key & 8191u);
        idx_g[(size_t)n*KNN + lane] = scene*NPER + j;
        u32 p = pc[scene*NPER + j];
        dx=(int)(p&255)-qx; dy=(int)((p>>8)&255)-qy; dz=(int)((p>>16)&255)-qz;
        size_t ro = ((size_t)n*KNN+lane)*3;
        rel[ro]=(float)dx; rel[ro+1]=(float)dy; rel[ro+2]=(float)dz;
    }
    int arr[9] = {dx,dy,dz, dx*dx,dy*dy,dz*dz, dx*dy,dx*dz,dy*dz};
#pragma unroll
    for (int o=32;o>=1;o>>=1)
#pragma unroll
        for (int j=0;j<9;j++) arr[j] += __shfl_xor(arr[j], o, 64);
    if (lane==0)
#pragma unroll
        for (int j=0;j<9;j++) atomicAdd(&red[j], (u64)(long long)arr[j]);
    __syncthreads();
    if (tid<9) atomicAdd(&sM[tid], red[tid]);
}

// ---------------------------------------------------------------- prep weights (transposed f16)
struct WPtrs { const float* p[5]; };
// types {0:W_top, 3:W_alp, 4:W_d2, 6:W_g2, 7:W_dn}; slots 1,2 (phi_g1, psi_g1) and 5 (d2_g1) filled later
__global__ __launch_bounds__(256) void prep_weights(WPtrs wp, u16* __restrict__ wt){
    const int tmap[5] = {0,3,4,6,7};
    int idx = blockIdx.x*256 + threadIdx.x;          // 5*2*16384
    int t = idx>>15, rem = idx&32767;
    int l = rem>>14, e = rem&16383;
    int n = e>>7, k = e&127;
    wt[(tmap[t]*2+l)*16384 + n*128 + k] = f2h(wp.p[t][l*16384 + k*128 + n]);
}

// analytic BN affine for the 3->H layer
__global__ __launch_bounds__(256) void finalize_d1(const u64* __restrict__ sM, const float* __restrict__ W_d1,
        const float* __restrict__ b_d1, const float* __restrict__ g, const float* __restrict__ beta,
        float* __restrict__ A, float* __restrict__ C){
    int tid=threadIdx.x; int l=tid>>7, c=tid&127;
    double s0=(double)(long long)sM[0], s1=(double)(long long)sM[1], s2=(double)(long long)sM[2];
    double m00=(double)(long long)sM[3], m11=(double)(long long)sM[4], m22=(double)(long long)sM[5];
    double m01=(double)(long long)sM[6], m02=(double)(long long)sM[7], m12=(double)(long long)sM[8];
    double w0=W_d1[l*384+c], w1=W_d1[l*384+128+c], w2=W_d1[l*384+256+c];
    double b =b_d1[l*128+c];
    double S = s0*w0+s1*w1+s2*w2;
    double Q = m00*w0*w0+m11*w1*w1+m22*w2*w2 + 2.0*(m01*w0*w1+m02*w0*w2+m12*w1*w2);
    double cnt = (double)NKROWS;
    double mean = S/cnt + b;
    double ex2  = (Q + 2.0*b*S)/cnt + b*b;
    double var  = ex2 - mean*mean;
    float a = g[l*128+c] * (float)(1.0/sqrt(var+1e-5));
    A[l*128+c]=a; C[l*128+c]=beta[l*128+c]-(float)mean*a;
}

// finalize BN affine from NSLOT fp64 partials; zeroes slots. Optional fused bias-combine:
// biasc[m] = b_g1[m] + sum_n (b_d2[n]*A[n]+C[n]) * Wg1[n][m]
__global__ void finalize_affine(double* __restrict__ P, const float* __restrict__ g,
        const float* __restrict__ b, double cnt, float* __restrict__ A, float* __restrict__ C,
        const float* __restrict__ Wg1, const float* __restrict__ b_d2, const float* __restrict__ b_g1,
        float* __restrict__ biasc){
    __shared__ float term[128];
    int c=threadIdx.x;
    double s=0.0, q=0.0;
#pragma unroll
    for (int k=0;k<NSLOT;k++){
        s+=P[k*256+c]; q+=P[k*256+128+c];
        P[k*256+c]=0.0; P[k*256+128+c]=0.0;
    }
    double mean=s/cnt, var=q/cnt-mean*mean;
    float a = g[c] * (float)(1.0/sqrt(var+1e-5));
    float cc = b[c]-(float)mean*a;
    A[c]=a; C[c]=cc;
    if (Wg1){
        term[c] = b_d2[c]*a + cc;
        __syncthreads();
        float acc = b_g1[c];
        for (int n=0;n<128;n++) acc += term[n]*Wg1[n*128+c];
        biasc[c] = acc;
    }
}

// ---------------------------------------------------------------- GEMM composers
struct CompF32 {
    const float* src;
    __device__ __forceinline__ void stage(u16* As,int R0,int k0,int tid) const {
#pragma unroll
        for (int u=0;u<8;u++){
            int flat=u*256+tid, row=flat>>4, c4=flat&15; int k=k0+c4*4;
            const float4 v=*(const float4*)(src+(size_t)(R0+row)*HD+k);
            ushort4 o; o.x=f2h(v.x); o.y=f2h(v.y); o.z=f2h(v.z); o.w=f2h(v.w);
            *(ushort4*)(As+row*72+c4*4)=o;
        }
    }
};
struct CompStatic {        // per-blockIdx.y f32 source (small weight-combine gemms)
    const float* p[4];
    __device__ __forceinline__ void stage(u16* As,int R0,int k0,int tid) const {
        const float* src = p[blockIdx.y];
#pragma unroll
        for (int u=0;u<8;u++){
            int flat=u*256+tid, row=flat>>4, c4=flat&15; int k=k0+c4*4;
            const float4 v=*(const float4*)(src+(size_t)(R0+row)*HD+k);
            ushort4 o; o.x=f2h(v.x); o.y=f2h(v.y); o.z=f2h(v.z); o.w=f2h(v.w);
            *(ushort4*)(As+row*72+c4*4)=o;
        }
    }
};
struct CompH16Aff {
    const u16* src; const float* Aa; const float* Ca;
    __device__ __forceinline__ void stage(u16* As,int R0,int k0,int tid) const {
#pragma unroll
        for (int u=0;u<8;u++){
            int flat=u*256+tid, row=flat>>4, c4=flat&15; int k=k0+c4*4;
            const ushort4 v=*(const ushort4*)(src+(size_t)(R0+row)*HD+k);
            ushort4 o;
            o.x=f2h(h2f(v.x)*Aa[k]  +Ca[k]);   o.y=f2h(h2f(v.y)*Aa[k+1]+Ca[k+1]);
            o.z=f2h(h2f(v.z)*Aa[k+2]+Ca[k+2]); o.w=f2h(h2f(v.w)*Aa[k+3]+Ca[k+3]);
            *(ushort4*)(As+row*72+c4*4)=o;
        }
    }
};
struct CompH16AffRelu {
    const u16* src; const float* Aa; const float* Ca;
    __device__ __forceinline__ void stage(u16* As,int R0,int k0,int tid) const {
#pragma unroll
        for (int u=0;u<8;u++){
            int flat=u*256+tid, row=flat>>4, c4=flat&15; int k=k0+c4*4;
            const ushort4 v=*(const ushort4*)(src+(size_t)(R0+row)*HD+k);
            ushort4 o;
            o.x=f2h(fmaxf(h2f(v.x)*Aa[k]  +Ca[k],  0.f));
            o.y=f2h(fmaxf(h2f(v.y)*Aa[k+1]+Ca[k+1],0.f));
            o.z=f2h(fmaxf(h2f(v.z)*Aa[k+2]+Ca[k+2],0.f));
            o.w=f2h(fmaxf(h2f(v.w)*Aa[k+3]+Ca[k+3],0.f));
            *(ushort4*)(As+row*72+c4*4)=o;
        }
    }
};
struct CompPose1 {         // relu(affine(rel @ W_d1 + b_d1)) computed on the fly (3 channels in)
    const float* rel; const float* Wd1; const float* bd1; const float* Aa; const float* Ca;
    __device__ __forceinline__ void stage(u16* As,int R0,int k0,int tid) const {
#pragma unroll
        for (int u=0;u<8;u++){
            int flat=u*256+tid, row=flat>>4, c4=flat&15; int k=k0+c4*4; int R=R0+row;
            float r0=rel[(size_t)R*3], r1=rel[(size_t)R*3+1], r2=rel[(size_t)R*3+2];
            ushort4 o;
#pragma unroll
            for (int j=0;j<4;j++){
                int kk=k+j;
                float x = r0*Wd1[kk] + r1*Wd1[HD+kk] + r2*Wd1[2*HD+kk] + bd1[kk];
                x = fmaxf(x*Aa[kk]+Ca[kk], 0.f);
                ((u16*)&o)[j]=f2h(x);
            }
            *(ushort4*)(As+row*72+c4*4)=o;
        }
    }
};

struct BTS { const float* p[4]; const float* scale; };

// ---------------------------------------------------------------- GEMM 128x128, K=128, MFMA f16
// BT: stage B transposed from f32 (optionally row-scaled) — for weight-combine gemms
// OUTT: store transposed (out[col][row]) — produces wt-layout combined weights
// EPIQK: epilogue adds q'[row>>4] - k'[gidx[row]] (vector-attention a1)
template<class Comp, bool OUT16, bool HASBIAS, bool STATS, bool EPIQK, bool BT, bool OUTT>
__global__ __launch_bounds__(256) void gemm128(Comp comp, const u16* __restrict__ Wt, BTS bts,
        const float* __restrict__ bias, void* __restrict__ outp, double* __restrict__ statsP,
        int wtStride, long outStride,
        const u16* __restrict__ eq, const u16* __restrict__ ek, const int* __restrict__ egidx){
    __shared__ __align__(16) u16 As[128*72];
    __shared__ __align__(16) u16 Bs[128*72];
    __shared__ float cs2[2][128], cq2[2][128];
    const u16* W = Wt + (size_t)blockIdx.y*wtStride;
    u16*   o16 = (u16*)outp   + (size_t)blockIdx.y*outStride;
    float* o32 = (float*)outp + (size_t)blockIdx.y*outStride;
    int tid=threadIdx.x;
    int R0=blockIdx.x*128;
    int lane=tid&63, wave=tid>>6, quad=lane>>4, r16=lane&15;
    int wm=wave>>1, wn=wave&1;
    floatx4 acc[4][4]={};
#pragma unroll
    for (int ks=0;ks<2;ks++){
        int k0=ks*64;
        comp.stage(As,R0,k0,tid);
        if (BT){
            const float* Bf = bts.p[blockIdx.y];
#pragma unroll
            for (int u=0;u<4;u++){
                int flat=u*256+tid, n=flat>>3, c8=flat&7;
                __align__(16) u16 tmp[8];
#pragma unroll
                for (int e=0;e<8;e++){
                    int k=k0+c8*8+e;
                    float v = Bf[(size_t)k*128+n];
                    if (bts.scale) v *= bts.scale[k];
                    tmp[e]=f2h(v);
                }
                *(int4*)(Bs+n*72+c8*8) = *(int4*)tmp;
            }
        } else {
#pragma unroll
            for (int u=0;u<4;u++){
                int flat=u*256+tid, n=flat>>3, c8=flat&7;
                *(int4*)(Bs+n*72+c8*8) = *(const int4*)(W+n*HD+k0+c8*8);
            }
        }
        __syncthreads();
#pragma unroll
        for (int kk2=0;kk2<2;kk2++){
            half8 aF[4], bF[4];
#pragma unroll
            for (int mi=0;mi<4;mi++) aF[mi]=*(const half8*)(As+(wm*64+mi*16+r16)*72 + kk2*32+quad*8);
#pragma unroll
            for (int ni=0;ni<4;ni++) bF[ni]=*(const half8*)(Bs+(wn*64+ni*16+r16)*72 + kk2*32+quad*8);
#pragma unroll
            for (int mi=0;mi<4;mi++)
#pragma unroll
                for (int ni=0;ni<4;ni++)
                    acc[mi][ni]=__builtin_amdgcn_mfma_f32_16x16x32_f16(aF[mi],bF[ni],acc[mi][ni],0,0,0);
        }
        __syncthreads();
    }
    float sAcc[4]={0,0,0,0}, qAcc[4]={0,0,0,0};
#pragma unroll
    for (int mi=0;mi<4;mi++)
#pragma unroll
        for (int rg=0;rg<4;rg++){
            int row=R0+wm*64+mi*16+quad*4+rg;
            int n16=0, gg=0;
            if (EPIQK){ n16=row>>4; gg=egidx[row]; }
#pragma unroll
            for (int ni=0;ni<4;ni++){
                int col=wn*64+ni*16+r16;
                float v=acc[mi][ni][rg] + (HASBIAS ? bias[col] : 0.f);
                if (EPIQK) v += h2f(eq[(size_t)n16*HD+col]) - h2f(ek[(size_t)gg*HD+col]);
                if (STATS){ sAcc[ni]+=v; qAcc[ni]+=v*v; }
                if (OUTT){
                    if (OUT16) o16[(size_t)col*HD+row]=f2h(v);
                    else       o32[(size_t)col*HD+row]=v;
                } else {
                    if (OUT16) o16[(size_t)row*HD+col]=f2h(v);
                    else       o32[(size_t)row*HD+col]=v;
                }
            }
        }
    if (STATS){
#pragma unroll
        for (int ni=0;ni<4;ni++){
            float s=sAcc[ni], q=qAcc[ni];
            s += __shfl_xor(s,16,64); s += __shfl_xor(s,32,64);
            q += __shfl_xor(q,16,64); q += __shfl_xor(q,32,64);
            if (quad==0){
                int col=wn*64+ni*16+r16;
                cs2[wm][col]=s; cq2[wm][col]=q;
            }
        }
        __syncthreads();
        if (tid<128){
            int slot = blockIdx.x & (NSLOT-1);
            unsafeAtomicAdd(&statsP[slot*256+tid],     (double)(cs2[0][tid]+cs2[1][tid]));
            unsafeAtomicAdd(&statsP[slot*256+128+tid], (double)(cq2[0][tid]+cq2[1][tid]));
        }
    }
}

// ---------------------------------------------------------------- softmax-aggregate + residual
__global__ __launch_bounds__(256) void aggregate(const u16* __restrict__ a2, const u16* __restrict__ pose,
        const u16* __restrict__ vv, const int* __restrict__ gidx,
        const float* __restrict__ Ag2, const float* __restrict__ Cg2,
        const float* __restrict__ Ad2, const float* __restrict__ Cd2, float* __restrict__ y){
    int c=(threadIdx.x&63)*2, h=threadIdx.x>>6;
    int n=blockIdx.x*4+h;
    float sA0=Ag2[c], sC0=Cg2[c], pA0=Ad2[c], pC0=Cd2[c];
    float sA1=Ag2[c+1], sC1=Cg2[c+1], pA1=Ad2[c+1], pC1=Cd2[c+1];
    float av0[16], av1[16]; float m0=-1e30f, m1=-1e30f;
#pragma unroll
    for (int k=0;k<16;k++){
        ushort2 t=*(const ushort2*)(a2+((size_t)n*16+k)*HD+c);
        float a0=h2f(t.x)*sA0+sC0, a1=h2f(t.y)*sA1+sC1;
        av0[k]=a0; av1[k]=a1; m0=fmaxf(m0,a0); m1=fmaxf(m1,a1);
    }
    float sum0=0.f, sum1=0.f;
#pragma unroll
    for (int k=0;k<16;k++){
        float e0=__expf(av0[k]-m0), e1=__expf(av1[k]-m1);
        av0[k]=e0; av1[k]=e1; sum0+=e0; sum1+=e1;
    }
    float acc0=0.f, acc1=0.f;
#pragma unroll
    for (int k=0;k<16;k++){
        int g=gidx[n*16+k];
        ushort2 pt=*(const ushort2*)(pose+((size_t)n*16+k)*HD+c);
        ushort2 vt=*(const ushort2*)(vv+(size_t)g*HD+c);
        acc0 += av0[k]*(h2f(pt.x)*pA0+pC0 + h2f(vt.x));
        acc1 += av1[k]*(h2f(pt.y)*pA1+pC1 + h2f(vt.y));
    }
    y[(size_t)n*HD+c]  =acc0/sum0;
    y[(size_t)n*HD+c+1]=acc1/sum1;
}

__global__ __launch_bounds__(256) void residual(const float* __restrict__ ydown, const float* __restrict__ A,
        const float* __restrict__ C, const float* __restrict__ fin, float* __restrict__ fout){
    size_t i=(size_t)blockIdx.x*256+threadIdx.x; int c=(int)(i&127);
    fout[i]=ydown[i]*A[c]+C[c]+fin[i];
}

// ---------------------------------------------------------------- launch
extern "C" void kernel_launch(void* const* d_in, const int* in_sizes, int n_in,
                              void* d_out, int out_size, void* d_ws, size_t ws_size,
                              hipStream_t stream){
    const int*   coords=(const int*)d_in[0];
    const float* feats=(const float*)d_in[1];
    const float* W_top=(const float*)d_in[2];
    const float* g_top=(const float*)d_in[3];
    const float* bt_top=(const float*)d_in[4];
    const float* W_phi=(const float*)d_in[5];
    const float* W_psi=(const float*)d_in[6];
    const float* W_alp=(const float*)d_in[7];
    const float* W_d1=(const float*)d_in[8];
    const float* b_d1=(const float*)d_in[9];
    const float* g_d1=(const float*)d_in[10];
    const float* bt_d1=(const float*)d_in[11];
    const float* W_d2=(const float*)d_in[12];
    const float* b_d2=(const float*)d_in[13];
    const float* g_d2=(const float*)d_in[14];
    const float* bt_d2=(const float*)d_in[15];
    const float* W_g1=(const float*)d_in[16];
    const float* b_g1=(const float*)d_in[17];
    const float* g_g1=(const float*)d_in[18];
    const float* bt_g1=(const float*)d_in[19];
    const float* W_g2=(const float*)d_in[20];
    const float* b_g2=(const float*)d_in[21];
    const float* g_g2=(const float*)d_in[22];
    const float* bt_g2=(const float*)d_in[23];
    const float* W_dn=(const float*)d_in[24];
    const float* g_dn=(const float*)d_in[25];
    const float* bt_dn=(const float*)d_in[26];

    char* ws=(char*)d_ws;
    size_t off=0;
    auto carve=[&](size_t bytes)->char*{ char* p=ws+off; off=(off+bytes+255)&~(size_t)255; return p; };
    u32*    pc    =(u32*)   carve((size_t)NPTS*4);
    uint2*  spt   =(uint2*) carve((size_t)NPTS*8);
    u32*    cs    =(u32*)   carve(1032*4);
    u32*    cptr  =(u32*)   carve(1024*4);
    int*    idxg  =(int*)   carve((size_t)NKROWS*4);
    float*  rel   =(float*) carve((size_t)NKROWS*3*4);
    u16*    h16   =(u16*)   carve((size_t)NPTS*HD*2);
    u16*    qb    =(u16*)   carve((size_t)3*NPTS*HD*2);   // q' | k' | v contiguous
    u16*    kpb   = qb + (size_t)NPTS*HD;
    u16*    vvb   = qb + (size_t)2*NPTS*HD;
    float*  yb    =(float*) carve((size_t)NPTS*HD*4);
    float*  ydown =(float*) carve((size_t)NPTS*HD*4);
    float*  fbuf  =(float*) carve((size_t)NPTS*HD*4);
    u16*    wt    =(u16*)   carve((size_t)8*2*16384*2);
    char*   stats =         carve(NSLOT*256*8 + 256 + 4096);   // P + sM + cellcnt
    double* P     =(double*)stats;
    u64*    sM    =(u64*)(stats + NSLOT*256*8);
    u32*    cellcnt=(u32*)(stats + NSLOT*256*8 + 256);
    float*  aff   =(float*) carve(8192);
    float *A_top=aff, *C_top=aff+128, *A_d2=aff+256, *C_d2=aff+384,
          *A_g1=aff+512, *C_g1=aff+640, *A_g2=aff+768, *C_g2=aff+896,
          *A_dn=aff+1024, *C_dn=aff+1152, *A_d1=aff+1280, *C_d1=aff+1536,
          *biasc=aff+1792;
    u16*    pose2 =(u16*)   carve((size_t)NKROWS*HD*2);
    u16*    abuf  =(u16*)   carve((size_t)NKROWS*HD*2);
    if (ws_size < off) return;

    BTS noBT{{nullptr,nullptr,nullptr,nullptr}, nullptr};

    hipMemsetAsync(stats, 0, NSLOT*256*8 + 256 + 4096, stream);
    pack_count<<<dim3(NPTS/256),dim3(256),0,stream>>>(coords, pc, cellcnt);
    prefix1024<<<dim3(1),dim3(1024),0,stream>>>(cellcnt, cs, cptr);
    scatter_pts<<<dim3(NPTS/256),dim3(256),0,stream>>>(pc, cptr, spt);
    WPtrs wp{{W_top,W_alp,W_d2,W_g2,W_dn}};
    prep_weights<<<dim3(5*2*16384/256),dim3(256),0,stream>>>(wp, wt);
    // static weight combines: slots (1,l) <- Wphi@Wg1, (2,l) <- Wpsi@Wg1 (transposed f16 out)
    {
        CompStatic cstat{{W_phi, W_phi+16384, W_psi, W_psi+16384}};
        BTS bts{{W_g1, W_g1+16384, W_g1, W_g1+16384}, nullptr};
        gemm128<CompStatic,true,false,false,false,true,true><<<dim3(1,4),dim3(256),0,stream>>>(
            cstat, nullptr, bts, nullptr, wt+2*16384, nullptr, 0, 16384, nullptr,nullptr,nullptr);
    }
    knn_grid<<<dim3(4096),dim3(256),0,stream>>>(pc, spt, cs, idxg, rel, sM);
    finalize_d1<<<dim3(1),dim3(256),0,stream>>>(sM, W_d1, b_d1, g_d1, bt_d1, A_d1, C_d1);

    const float* fin=feats;
    for (int l=0;l<2;l++){
        const u16* wt_top=wt+(0*2+l)*16384;
        const u16* wt_d2 =wt+(4*2+l)*16384;
        const u16* wt_c  =wt+(5*2+l)*16384;   // dynamic d2_g1 combined
        const u16* wt_g2 =wt+(6*2+l)*16384;
        const u16* wt_dn =wt+(7*2+l)*16384;

        // h16 = f @ W_top (f16 out, stats fused)
        gemm128<CompF32,true,false,true,false,false,false><<<dim3(NPTS/128),dim3(256),0,stream>>>(
            CompF32{fin}, wt_top, noBT, nullptr, h16, P, 0, 0, nullptr,nullptr,nullptr);
        finalize_affine<<<dim3(1),dim3(128),0,stream>>>(P, g_top+l*128, bt_top+l*128, (double)NPTS,
            A_top, C_top, nullptr,nullptr,nullptr,nullptr);

        // q' / k' / v in ONE launch (weights slots 1,2,3 stride 2*16384)
        gemm128<CompH16Aff,true,false,false,false,false,false><<<dim3(NPTS/128,3),dim3(256),0,stream>>>(
            CompH16Aff{h16,A_top,C_top}, wt+(1*2+l)*16384, noBT, nullptr, qb, nullptr,
            2*16384, (long)NPTS*HD, nullptr,nullptr,nullptr);

        // pose2 = relu(BN1(rel@W_d1+b_d1)) @ W_d2 + b_d2 (stats fused)
        gemm128<CompPose1,true,true,true,false,false,false><<<dim3(NKROWS/128),dim3(256),0,stream>>>(
            CompPose1{rel, W_d1+l*384, b_d1+l*128, A_d1+l*128, C_d1+l*128}, wt_d2, noBT,
            b_d2+l*128, pose2, P, 0, 0, nullptr,nullptr,nullptr);
        finalize_affine<<<dim3(1),dim3(128),0,stream>>>(P, g_d2+l*128, bt_d2+l*128, (double)NKROWS,
            A_d2, C_d2, W_g1+l*16384, b_d2+l*128, b_g1+l*128, biasc);

        // dynamic combine: slot (5,l) <- W_d2 @ diag(A_d2) @ W_g1
        {
            CompStatic cd{{W_d2+l*16384, nullptr, nullptr, nullptr}};
            BTS bts{{W_g1+l*16384, nullptr, nullptr, nullptr}, A_d2};
            gemm128<CompStatic,true,false,false,false,true,true><<<dim3(1,1),dim3(256),0,stream>>>(
                cd, nullptr, bts, nullptr, (void*)wt_c, nullptr, 0, 0, nullptr,nullptr,nullptr);
        }

        // a1 = pose1 @ Wcomb + (q'[n] - k'[g]) + biasc   (stats fused)
        gemm128<CompPose1,true,true,true,true,false,false><<<dim3(NKROWS/128),dim3(256),0,stream>>>(
            CompPose1{rel, W_d1+l*384, b_d1+l*128, A_d1+l*128, C_d1+l*128}, wt_c, noBT,
            biasc, abuf, P, 0, 0, qb, kpb, idxg);
        finalize_affine<<<dim3(1),dim3(128),0,stream>>>(P, g_g1+l*128, bt_g1+l*128, (double)NKROWS,
            A_g1, C_g1, nullptr,nullptr,nullptr,nullptr);

        // a2 = relu(BN(a1)) @ W_g2 + b_g2 (in-place, stats fused)
        gemm128<CompH16AffRelu,true,true,true,false,false,false><<<dim3(NKROWS/128),dim3(256),0,stream>>>(
            CompH16AffRelu{abuf,A_g1,C_g1}, wt_g2, noBT, b_g2+l*128, abuf, P, 0, 0, nullptr,nullptr,nullptr);
        finalize_affine<<<dim3(1),dim3(128),0,stream>>>(P, g_g2+l*128, bt_g2+l*128, (double)NKROWS,
            A_g2, C_g2, nullptr,nullptr,nullptr,nullptr);

        // softmax over K + aggregate
        aggregate<<<dim3(NPTS/4),dim3(256),0,stream>>>(abuf, pose2, vvb, idxg, A_g2, C_g2, A_d2, C_d2, yb);

        // y @ W_down (stats fused) ; BN ; residual
        gemm128<CompF32,false,false,true,false,false,false><<<dim3(NPTS/128),dim3(256),0,stream>>>(
            CompF32{yb}, wt_dn, noBT, nullptr, ydown, P, 0, 0, nullptr,nullptr,nullptr);
        finalize_affine<<<dim3(1),dim3(128),0,stream>>>(P, g_dn+l*128, bt_dn+l*128, (double)NPTS,
            A_dn, C_dn, nullptr,nullptr,nullptr,nullptr);
        residual<<<dim3(NPTS*HD/256),dim3(256),0,stream>>>(ydown, A_dn, C_dn, fin, (l==1)?(float*)d_out:fbuf);
        fin=fbuf;
    }
}

// Round 5
// 677.395 us; speedup vs baseline: 1.0410x; 1.0410x over previous
//
#include <hip/hip_runtime.h>

using u16 = unsigned short;
using u32 = unsigned int;
using u64 = unsigned long long;

#define NPTS   16384
#define NPER   8192
#define KNN    16
#define NKROWS (NPTS*KNN)
#define HD     128
#define KCAP   512   // knn per-wave candidate buffer slots
#define NSLOT  16    // fp64 stats partial slots

typedef _Float16 half8 __attribute__((ext_vector_type(8)));
typedef float    floatx4 __attribute__((ext_vector_type(4)));

__device__ __forceinline__ u16  f2h(float f){ _Float16 h=(_Float16)f; return __builtin_bit_cast(u16,h); }
__device__ __forceinline__ float h2f(u16 u){ return (float)__builtin_bit_cast(_Float16,u); }
__device__ __forceinline__ u32 umin32(u32 a,u32 b){ return a<b?a:b; }
__device__ __forceinline__ int cell_of(int x){ return (x*5243)>>17; }   // exact /25 for 0..255

// ---------------------------------------------------------------- grid build
__global__ __launch_bounds__(256) void pack_count(const int* __restrict__ coords, u32* __restrict__ pc,
                                                  u32* __restrict__ cellcnt){
    int i = blockIdx.x*256 + threadIdx.x;
    int x=coords[3*i], y=coords[3*i+1], z=coords[3*i+2];
    pc[i] = (u32)x | ((u32)y<<8) | ((u32)z<<16);
    int cid = ((cell_of(z)*8 + cell_of(y))<<3) + cell_of(x);
    atomicAdd(&cellcnt[(i>>13)*512 + cid], 1u);
}

__global__ __launch_bounds__(1024) void prefix1024(const u32* __restrict__ cellcnt,
                                                   u32* __restrict__ cs, u32* __restrict__ cptr){
    __shared__ u32 tmp[1024];
    int t = threadIdx.x;
    u32 mine = cellcnt[t];
    tmp[t] = mine;
    __syncthreads();
    for (int off=1; off<1024; off<<=1){
        u32 v = (t>=off) ? tmp[t-off] : 0u;
        __syncthreads();
        tmp[t] += v;
        __syncthreads();
    }
    if (t==0) cs[0]=0;
    cs[t+1] = tmp[t];
    cptr[t] = tmp[t] - mine;
}

__global__ __launch_bounds__(256) void scatter_pts(const u32* __restrict__ pc, u32* __restrict__ cptr,
                                                   uint2* __restrict__ spt){
    int i = blockIdx.x*256 + threadIdx.x;
    u32 p = pc[i];
    int cid = ((cell_of((int)((p>>16)&255))*8 + cell_of((int)((p>>8)&255)))<<3) + cell_of((int)(p&255));
    u32 pos = atomicAdd(&cptr[(i>>13)*512 + cid], 1u);
    spt[pos] = make_uint2(p, (u32)(i&8191));
}

// ---------------------------------------------------------------- KNN: grid-bucketed, wave-per-query
__global__ __launch_bounds__(256) void knn_grid(const u32* __restrict__ pc, const uint2* __restrict__ spt,
                                                const u32* __restrict__ cs, int* __restrict__ idx_g,
                                                float* __restrict__ rel, u64* __restrict__ sM){
    __shared__ u32 buf[4][KCAP];
    __shared__ u64 red[9];
    int tid = threadIdx.x;
    int wave = tid>>6, lane = tid&63;
    int scene = blockIdx.x >> 11;
    int q = (blockIdx.x & 2047)*4 + wave;
    if (tid<9) red[tid]=0;
    if (lane<16) buf[wave][lane]=0xFFFFFFFFu;
    __syncthreads();

    u32 qp = pc[scene*NPER + q];
    int qx=(int)(qp&255), qy=(int)((qp>>8)&255), qz=(int)((qp>>16)&255);
    int cx=cell_of(qx), cy=cell_of(qy), cz=cell_of(qz);
    u32 thresh = 0xFFFFFFFFu;
    u32 cnt = 16;

    auto merge = [&](){
        u32 v[8];
#pragma unroll
        for (int r=0;r<8;r++) v[r] = ((u32)(lane + r*64) < cnt) ? buf[wave][lane + r*64] : 0xFFFFFFFFu;
        u32 out = 0;
#pragma unroll
        for (int it=0; it<16; it++){
            u32 m = umin32(umin32(umin32(v[0],v[1]),umin32(v[2],v[3])),
                           umin32(umin32(v[4],v[5]),umin32(v[6],v[7])));
#pragma unroll
            for (int o=32;o>=1;o>>=1) m = umin32(m, (u32)__shfl_xor((int)m, o, 64));
#pragma unroll
            for (int r=0;r<8;r++) if (v[r]==m) v[r]=0xFFFFFFFFu;
            if (lane==it) out = m;
            thresh = m;
        }
        if (lane<16) buf[wave][lane] = out;
        cnt = 16;
    };

    auto scan64 = [&](u32 key){
        u64 mask = __ballot(key < thresh);
        if (mask){
            u32 lt = __builtin_amdgcn_mbcnt_hi((u32)(mask>>32), __builtin_amdgcn_mbcnt_lo((u32)mask,0));
            if (key < thresh) buf[wave][cnt + lt] = key;
            cnt += (u32)__popcll(mask);
            if (cnt > KCAP-64) merge();
        }
    };

    int x0 = cx>0?cx-1:0, x1 = cx<7?cx+1:7;
    int y0 = cy>0?cy-1:0, y1 = cy<7?cy+1:7;
    int z0 = cz>0?cz-1:0, z1 = cz<7?cz+1:7;
    int sbase = scene*512;
    int nx = x1-x0+1;
    for (int rz=z0; rz<=z1; rz++)
        for (int ry=y0; ry<=y1; ry++){
            int c0 = sbase + ((rz*8+ry)<<3) + x0;
            int s = (int)cs[c0], e = (int)cs[c0+nx];
            for (int i=s; i<e; i+=64){
                int p = i + lane;
                u32 key = 0xFFFFFFFFu;
                if (p < e){
                    uint2 pt = spt[p];
                    int dx=(int)(pt.x&255)-qx, dy=(int)((pt.x>>8)&255)-qy, dz=(int)((pt.x>>16)&255)-qz;
                    u32 d2 = (u32)(__mul24(dx,dx)+__mul24(dy,dy)+__mul24(dz,dz));
                    key = (d2<<13) | pt.y;
                }
                scan64(key);
            }
        }
    merge();

    // exactness check vs unclipped window faces
    int d2_16 = (int)(thresh>>13);
    int mxl = (cx==0)?1000: qx - 25*(cx-1);
    int mxr = (cx==7)?1000: 25*(cx+2) - qx;
    int myl = (cy==0)?1000: qy - 25*(cy-1);
    int myr = (cy==7)?1000: 25*(cy+2) - qy;
    int mzl = (cz==0)?1000: qz - 25*(cz-1);
    int mzr = (cz==7)?1000: 25*(cz+2) - qz;
    int m = min(min(min(mxl,mxr),min(myl,myr)),min(mzl,mzr));
    if (d2_16 > m*m){                       // rare: exact full-scan fallback
        thresh = 0xFFFFFFFFu; cnt = 16;
        if (lane<16) buf[wave][lane]=0xFFFFFFFFu;
        const u32* sp = pc + scene*NPER;
        for (int t=0;t<128;t++){
            u32 p = sp[t*64+lane];
            int dx=(int)(p&255)-qx, dy=(int)((p>>8)&255)-qy, dz=(int)((p>>16)&255)-qz;
            u32 d2 = (u32)(__mul24(dx,dx)+__mul24(dy,dy)+__mul24(dz,dz));
            scan64((d2<<13) | (u32)(t*64+lane));
        }
        merge();
    }

    int n = scene*NPER + q;
    u32 key = buf[wave][lane & 15];
    int dx=0,dy=0,dz=0;
    if (lane<16){
        int j = (int)(key & 8191u);
        idx_g[(size_t)n*KNN + lane] = scene*NPER + j;
        u32 p = pc[scene*NPER + j];
        dx=(int)(p&255)-qx; dy=(int)((p>>8)&255)-qy; dz=(int)((p>>16)&255)-qz;
        size_t ro = ((size_t)n*KNN+lane)*3;
        rel[ro]=(float)dx; rel[ro+1]=(float)dy; rel[ro+2]=(float)dz;
    }
    int arr[9] = {dx,dy,dz, dx*dx,dy*dy,dz*dz, dx*dy,dx*dz,dy*dz};
#pragma unroll
    for (int o=32;o>=1;o>>=1)
#pragma unroll
        for (int j=0;j<9;j++) arr[j] += __shfl_xor(arr[j], o, 64);
    if (lane==0)
#pragma unroll
        for (int j=0;j<9;j++) atomicAdd(&red[j], (u64)(long long)arr[j]);
    __syncthreads();
    if (tid<9) atomicAdd(&sM[tid], red[tid]);
}

// ---------------------------------------------------------------- prep weights (transposed f16)
struct WPtrs { const float* p[5]; };
__global__ __launch_bounds__(256) void prep_weights(WPtrs wp, u16* __restrict__ wt){
    const int tmap[5] = {0,3,4,6,7};
    int idx = blockIdx.x*256 + threadIdx.x;          // 5*2*16384
    int t = idx>>15, rem = idx&32767;
    int l = rem>>14, e = rem&16383;
    int n = e>>7, k = e&127;
    wt[(tmap[t]*2+l)*16384 + n*128 + k] = f2h(wp.p[t][l*16384 + k*128 + n]);
}

// analytic BN affine for the 3->H layer
__global__ __launch_bounds__(256) void finalize_d1(const u64* __restrict__ sM, const float* __restrict__ W_d1,
        const float* __restrict__ b_d1, const float* __restrict__ g, const float* __restrict__ beta,
        float* __restrict__ A, float* __restrict__ C){
    int tid=threadIdx.x; int l=tid>>7, c=tid&127;
    double s0=(double)(long long)sM[0], s1=(double)(long long)sM[1], s2=(double)(long long)sM[2];
    double m00=(double)(long long)sM[3], m11=(double)(long long)sM[4], m22=(double)(long long)sM[5];
    double m01=(double)(long long)sM[6], m02=(double)(long long)sM[7], m12=(double)(long long)sM[8];
    double w0=W_d1[l*384+c], w1=W_d1[l*384+128+c], w2=W_d1[l*384+256+c];
    double b =b_d1[l*128+c];
    double S = s0*w0+s1*w1+s2*w2;
    double Q = m00*w0*w0+m11*w1*w1+m22*w2*w2 + 2.0*(m01*w0*w1+m02*w0*w2+m12*w1*w2);
    double cnt = (double)NKROWS;
    double mean = S/cnt + b;
    double ex2  = (Q + 2.0*b*S)/cnt + b*b;
    double var  = ex2 - mean*mean;
    float a = g[l*128+c] * (float)(1.0/sqrt(var+1e-5));
    A[l*128+c]=a; C[l*128+c]=beta[l*128+c]-(float)mean*a;
}

// finalize BN affine from NSLOT fp64 partials; zeroes slots. Optional fused bias-combine.
__global__ void finalize_affine(double* __restrict__ P, const float* __restrict__ g,
        const float* __restrict__ b, double cnt, float* __restrict__ A, float* __restrict__ C,
        const float* __restrict__ Wg1, const float* __restrict__ b_d2, const float* __restrict__ b_g1,
        float* __restrict__ biasc){
    __shared__ float term[128];
    int c=threadIdx.x;
    double s=0.0, q=0.0;
#pragma unroll
    for (int k=0;k<NSLOT;k++){
        s+=P[k*256+c]; q+=P[k*256+128+c];
        P[k*256+c]=0.0; P[k*256+128+c]=0.0;
    }
    double mean=s/cnt, var=q/cnt-mean*mean;
    float a = g[c] * (float)(1.0/sqrt(var+1e-5));
    float cc = b[c]-(float)mean*a;
    A[c]=a; C[c]=cc;
    if (Wg1){
        term[c] = b_d2[c]*a + cc;
        __syncthreads();
        float acc = b_g1[c];
        for (int n=0;n<128;n++) acc += term[n]*Wg1[n*128+c];
        biasc[c] = acc;
    }
}

// ---------------------------------------------------------------- GEMM composers
struct CompF32 {
    const float* src;
    __device__ __forceinline__ void stage(u16* As,int R0,int k0,int tid) const {
#pragma unroll
        for (int u=0;u<8;u++){
            int flat=u*256+tid, row=flat>>4, c4=flat&15; int k=k0+c4*4;
            const float4 v=*(const float4*)(src+(size_t)(R0+row)*HD+k);
            ushort4 o; o.x=f2h(v.x); o.y=f2h(v.y); o.z=f2h(v.z); o.w=f2h(v.w);
            *(ushort4*)(As+row*72+c4*4)=o;
        }
    }
};
struct CompH16 {           // plain f16 row copy
    const u16* src;
    __device__ __forceinline__ void stage(u16* As,int R0,int k0,int tid) const {
#pragma unroll
        for (int u=0;u<8;u++){
            int flat=u*256+tid, row=flat>>4, c4=flat&15; int k=k0+c4*4;
            *(ushort4*)(As+row*72+c4*4) = *(const ushort4*)(src+(size_t)(R0+row)*HD+k);
        }
    }
};
struct CompStatic {        // per-blockIdx.y f32 source (weight-combine gemms)
    const float* p[4];
    __device__ __forceinline__ void stage(u16* As,int R0,int k0,int tid) const {
        const float* src = p[blockIdx.y];
#pragma unroll
        for (int u=0;u<8;u++){
            int flat=u*256+tid, row=flat>>4, c4=flat&15; int k=k0+c4*4;
            const float4 v=*(const float4*)(src+(size_t)(R0+row)*HD+k);
            ushort4 o; o.x=f2h(v.x); o.y=f2h(v.y); o.z=f2h(v.z); o.w=f2h(v.w);
            *(ushort4*)(As+row*72+c4*4)=o;
        }
    }
};
struct CompH16Aff {
    const u16* src; const float* Aa; const float* Ca;
    __device__ __forceinline__ void stage(u16* As,int R0,int k0,int tid) const {
#pragma unroll
        for (int u=0;u<8;u++){
            int flat=u*256+tid, row=flat>>4, c4=flat&15; int k=k0+c4*4;
            const ushort4 v=*(const ushort4*)(src+(size_t)(R0+row)*HD+k);
            ushort4 o;
            o.x=f2h(h2f(v.x)*Aa[k]  +Ca[k]);   o.y=f2h(h2f(v.y)*Aa[k+1]+Ca[k+1]);
            o.z=f2h(h2f(v.z)*Aa[k+2]+Ca[k+2]); o.w=f2h(h2f(v.w)*Aa[k+3]+Ca[k+3]);
            *(ushort4*)(As+row*72+c4*4)=o;
        }
    }
};
struct CompH16AffRelu {
    const u16* src; const float* Aa; const float* Ca;
    __device__ __forceinline__ void stage(u16* As,int R0,int k0,int tid) const {
#pragma unroll
        for (int u=0;u<8;u++){
            int flat=u*256+tid, row=flat>>4, c4=flat&15; int k=k0+c4*4;
            const ushort4 v=*(const ushort4*)(src+(size_t)(R0+row)*HD+k);
            ushort4 o;
            o.x=f2h(fmaxf(h2f(v.x)*Aa[k]  +Ca[k],  0.f));
            o.y=f2h(fmaxf(h2f(v.y)*Aa[k+1]+Ca[k+1],0.f));
            o.z=f2h(fmaxf(h2f(v.z)*Aa[k+2]+Ca[k+2],0.f));
            o.w=f2h(fmaxf(h2f(v.w)*Aa[k+3]+Ca[k+3],0.f));
            *(ushort4*)(As+row*72+c4*4)=o;
        }
    }
};
struct CompPose1 {         // relu(affine(rel @ W_d1 + b_d1)) on the fly (3 channels in)
    const float* rel; const float* Wd1; const float* bd1; const float* Aa; const float* Ca;
    __device__ __forceinline__ void stage(u16* As,int R0,int k0,int tid) const {
#pragma unroll
        for (int u=0;u<8;u++){
            int flat=u*256+tid, row=flat>>4, c4=flat&15; int k=k0+c4*4; int R=R0+row;
            float r0=rel[(size_t)R*3], r1=rel[(size_t)R*3+1], r2=rel[(size_t)R*3+2];
            ushort4 o;
#pragma unroll
            for (int j=0;j<4;j++){
                int kk=k+j;
                float x = r0*Wd1[kk] + r1*Wd1[HD+kk] + r2*Wd1[2*HD+kk] + bd1[kk];
                x = fmaxf(x*Aa[kk]+Ca[kk], 0.f);
                ((u16*)&o)[j]=f2h(x);
            }
            *(ushort4*)(As+row*72+c4*4)=o;
        }
    }
};

struct BTS { const float* p[4]; const float* scale; };

// ---------------------------------------------------------------- GEMM 128x128, K=128, MFMA f16
// EPIQK: epilogue adds q'[row>>4] - k'[gidx[row]] via LDS-staged rows (coalesced gather)
template<class Comp, bool OUT16, bool HASBIAS, bool STATS, bool EPIQK, bool BT, bool OUTT>
__global__ __launch_bounds__(256) void gemm128(Comp comp, const u16* __restrict__ Wt, BTS bts,
        const float* __restrict__ bias, void* __restrict__ outp, double* __restrict__ statsP,
        int wtStride, long outStride,
        const u16* __restrict__ eq, const u16* __restrict__ ek, const int* __restrict__ egidx){
    __shared__ __align__(16) u16 smem[2*128*72];   // As | Bs; reused as qk-stage for EPIQK
    u16* As = smem;
    u16* Bs = smem + 128*72;
    __shared__ float cs2[2][128], cq2[2][128];
    const u16* W = Wt + (size_t)blockIdx.y*wtStride;
    u16*   o16 = (u16*)outp   + (size_t)blockIdx.y*outStride;
    float* o32 = (float*)outp + (size_t)blockIdx.y*outStride;
    int tid=threadIdx.x;
    int R0=blockIdx.x*128;
    int lane=tid&63, wave=tid>>6, quad=lane>>4, r16=lane&15;
    int wm=wave>>1, wn=wave&1;
    floatx4 acc[4][4]={};
#pragma unroll
    for (int ks=0;ks<2;ks++){
        int k0=ks*64;
        comp.stage(As,R0,k0,tid);
        if (BT){
            const float* Bf = bts.p[blockIdx.y];
#pragma unroll
            for (int u=0;u<4;u++){
                int flat=u*256+tid, n=flat>>3, c8=flat&7;
                __align__(16) u16 tmp[8];
#pragma unroll
                for (int e=0;e<8;e++){
                    int k=k0+c8*8+e;
                    float v = Bf[(size_t)k*128+n];
                    if (bts.scale) v *= bts.scale[k];
                    tmp[e]=f2h(v);
                }
                *(int4*)(Bs+n*72+c8*8) = *(int4*)tmp;
            }
        } else {
#pragma unroll
            for (int u=0;u<4;u++){
                int flat=u*256+tid, n=flat>>3, c8=flat&7;
                *(int4*)(Bs+n*72+c8*8) = *(const int4*)(W+n*HD+k0+c8*8);
            }
        }
        __syncthreads();
#pragma unroll
        for (int kk2=0;kk2<2;kk2++){
            half8 aF[4], bF[4];
#pragma unroll
            for (int mi=0;mi<4;mi++) aF[mi]=*(const half8*)(As+(wm*64+mi*16+r16)*72 + kk2*32+quad*8);
#pragma unroll
            for (int ni=0;ni<4;ni++) bF[ni]=*(const half8*)(Bs+(wn*64+ni*16+r16)*72 + kk2*32+quad*8);
#pragma unroll
            for (int mi=0;mi<4;mi++)
#pragma unroll
                for (int ni=0;ni<4;ni++)
                    acc[mi][ni]=__builtin_amdgcn_mfma_f32_16x16x32_f16(aF[mi],bF[ni],acc[mi][ni],0,0,0);
        }
        __syncthreads();
    }
    if (EPIQK){
        // stage k' rows gidx[R0+r] (r=0..127) and q' rows (R0>>4)+0..7 (r=128..135)
        // row stride 132 u16 (264B): rows r, r+4 land 8 banks apart -> conflict-free epilogue reads
#pragma unroll
        for (int u=0;u<17;u++){
            int task = u*256 + tid;              // 136 rows x 32 chunks = 4352 = 17*256
            int r = task >> 5, ch = task & 31;
            const u16* src = (r < 128) ? (ek + (size_t)egidx[R0+r]*HD)
                                       : (eq + ((size_t)(R0>>4) + (r-128))*HD);
            *(ushort4*)(smem + r*132 + ch*4) = *(const ushort4*)(src + ch*4);
        }
        __syncthreads();
    }
    float sAcc[4]={0,0,0,0}, qAcc[4]={0,0,0,0};
#pragma unroll
    for (int mi=0;mi<4;mi++){
        float qv[4]={0,0,0,0};
        if (EPIQK){
            int n16l = wm*4+mi;                  // wave-uniform q row for this mi
#pragma unroll
            for (int ni=0;ni<4;ni++) qv[ni]=h2f(smem[(128+n16l)*132 + wn*64+ni*16+r16]);
        }
#pragma unroll
        for (int rg=0;rg<4;rg++){
            int rloc = wm*64+mi*16+quad*4+rg;
            int row = R0+rloc;
#pragma unroll
            for (int ni=0;ni<4;ni++){
                int col=wn*64+ni*16+r16;
                float v=acc[mi][ni][rg] + (HASBIAS ? bias[col] : 0.f);
                if (EPIQK) v += qv[ni] - h2f(smem[rloc*132+col]);
                if (STATS){ sAcc[ni]+=v; qAcc[ni]+=v*v; }
                if (OUTT){
                    if (OUT16) o16[(size_t)col*HD+row]=f2h(v);
                    else       o32[(size_t)col*HD+row]=v;
                } else {
                    if (OUT16) o16[(size_t)row*HD+col]=f2h(v);
                    else       o32[(size_t)row*HD+col]=v;
                }
            }
        }
    }
    if (STATS){
#pragma unroll
        for (int ni=0;ni<4;ni++){
            float s=sAcc[ni], q=qAcc[ni];
            s += __shfl_xor(s,16,64); s += __shfl_xor(s,32,64);
            q += __shfl_xor(q,16,64); q += __shfl_xor(q,32,64);
            if (quad==0){
                int col=wn*64+ni*16+r16;
                cs2[wm][col]=s; cq2[wm][col]=q;
            }
        }
        __syncthreads();
        if (tid<128){
            int slot = blockIdx.x & (NSLOT-1);
            unsafeAtomicAdd(&statsP[slot*256+tid],     (double)(cs2[0][tid]+cs2[1][tid]));
            unsafeAtomicAdd(&statsP[slot*256+128+tid], (double)(cq2[0][tid]+cq2[1][tid]));
        }
    }
}

// ---------------------------------------------------------------- softmax-aggregate + residual
__global__ __launch_bounds__(256) void aggregate(const u16* __restrict__ a2, const u16* __restrict__ pose,
        const u16* __restrict__ vv, const int* __restrict__ gidx,
        const float* __restrict__ Ag2, const float* __restrict__ Cg2,
        const float* __restrict__ Ad2, const float* __restrict__ Cd2, u16* __restrict__ y){
    int c=(threadIdx.x&63)*2, h=threadIdx.x>>6;
    int n=blockIdx.x*4+h;
    float sA0=Ag2[c], sC0=Cg2[c], pA0=Ad2[c], pC0=Cd2[c];
    float sA1=Ag2[c+1], sC1=Cg2[c+1], pA1=Ad2[c+1], pC1=Cd2[c+1];
    float av0[16], av1[16]; float m0=-1e30f, m1=-1e30f;
#pragma unroll
    for (int k=0;k<16;k++){
        ushort2 t=*(const ushort2*)(a2+((size_t)n*16+k)*HD+c);
        float a0=h2f(t.x)*sA0+sC0, a1=h2f(t.y)*sA1+sC1;
        av0[k]=a0; av1[k]=a1; m0=fmaxf(m0,a0); m1=fmaxf(m1,a1);
    }
    float sum0=0.f, sum1=0.f;
#pragma unroll
    for (int k=0;k<16;k++){
        float e0=__expf(av0[k]-m0), e1=__expf(av1[k]-m1);
        av0[k]=e0; av1[k]=e1; sum0+=e0; sum1+=e1;
    }
    float acc0=0.f, acc1=0.f;
#pragma unroll
    for (int k=0;k<16;k++){
        int g=gidx[n*16+k];
        ushort2 pt=*(const ushort2*)(pose+((size_t)n*16+k)*HD+c);
        ushort2 vt=*(const ushort2*)(vv+(size_t)g*HD+c);
        acc0 += av0[k]*(h2f(pt.x)*pA0+pC0 + h2f(vt.x));
        acc1 += av1[k]*(h2f(pt.y)*pA1+pC1 + h2f(vt.y));
    }
    ushort2 o; o.x=f2h(acc0/sum0); o.y=f2h(acc1/sum1);
    *(ushort2*)(y+(size_t)n*HD+c)=o;
}

__global__ __launch_bounds__(256) void residual(const float* __restrict__ ydown, const float* __restrict__ A,
        const float* __restrict__ C, const float* __restrict__ fin, float* __restrict__ fout){
    size_t i=(size_t)blockIdx.x*256+threadIdx.x; int c=(int)(i&127);
    fout[i]=ydown[i]*A[c]+C[c]+fin[i];
}

// ---------------------------------------------------------------- launch
extern "C" void kernel_launch(void* const* d_in, const int* in_sizes, int n_in,
                              void* d_out, int out_size, void* d_ws, size_t ws_size,
                              hipStream_t stream){
    const int*   coords=(const int*)d_in[0];
    const float* feats=(const float*)d_in[1];
    const float* W_top=(const float*)d_in[2];
    const float* g_top=(const float*)d_in[3];
    const float* bt_top=(const float*)d_in[4];
    const float* W_phi=(const float*)d_in[5];
    const float* W_psi=(const float*)d_in[6];
    const float* W_alp=(const float*)d_in[7];
    const float* W_d1=(const float*)d_in[8];
    const float* b_d1=(const float*)d_in[9];
    const float* g_d1=(const float*)d_in[10];
    const float* bt_d1=(const float*)d_in[11];
    const float* W_d2=(const float*)d_in[12];
    const float* b_d2=(const float*)d_in[13];
    const float* g_d2=(const float*)d_in[14];
    const float* bt_d2=(const float*)d_in[15];
    const float* W_g1=(const float*)d_in[16];
    const float* b_g1=(const float*)d_in[17];
    const float* g_g1=(const float*)d_in[18];
    const float* bt_g1=(const float*)d_in[19];
    const float* W_g2=(const float*)d_in[20];
    const float* b_g2=(const float*)d_in[21];
    const float* g_g2=(const float*)d_in[22];
    const float* bt_g2=(const float*)d_in[23];
    const float* W_dn=(const float*)d_in[24];
    const float* g_dn=(const float*)d_in[25];
    const float* bt_dn=(const float*)d_in[26];

    char* ws=(char*)d_ws;
    size_t off=0;
    auto carve=[&](size_t bytes)->char*{ char* p=ws+off; off=(off+bytes+255)&~(size_t)255; return p; };
    u32*    pc    =(u32*)   carve((size_t)NPTS*4);
    uint2*  spt   =(uint2*) carve((size_t)NPTS*8);
    u32*    cs    =(u32*)   carve(1032*4);
    u32*    cptr  =(u32*)   carve(1024*4);
    int*    idxg  =(int*)   carve((size_t)NKROWS*4);
    float*  rel   =(float*) carve((size_t)NKROWS*3*4);
    u16*    h16   =(u16*)   carve((size_t)NPTS*HD*2);
    u16*    qb    =(u16*)   carve((size_t)3*NPTS*HD*2);   // q' | k' | v contiguous
    u16*    kpb   = qb + (size_t)NPTS*HD;
    u16*    vvb   = qb + (size_t)2*NPTS*HD;
    u16*    yb    =(u16*)   carve((size_t)NPTS*HD*2);
    float*  ydown =(float*) carve((size_t)NPTS*HD*4);
    float*  fbuf  =(float*) carve((size_t)NPTS*HD*4);
    u16*    wt    =(u16*)   carve((size_t)8*2*16384*2);
    char*   stats =         carve(NSLOT*256*8 + 256 + 4096);   // P + sM + cellcnt
    double* P     =(double*)stats;
    u64*    sM    =(u64*)(stats + NSLOT*256*8);
    u32*    cellcnt=(u32*)(stats + NSLOT*256*8 + 256);
    float*  aff   =(float*) carve(8192);
    float *A_top=aff, *C_top=aff+128, *A_d2=aff+256, *C_d2=aff+384,
          *A_g1=aff+512, *C_g1=aff+640, *A_g2=aff+768, *C_g2=aff+896,
          *A_dn=aff+1024, *C_dn=aff+1152, *A_d1=aff+1280, *C_d1=aff+1536,
          *biasc=aff+1792;
    u16*    pose2 =(u16*)   carve((size_t)NKROWS*HD*2);
    u16*    abuf  =(u16*)   carve((size_t)NKROWS*HD*2);
    if (ws_size < off) return;

    BTS noBT{{nullptr,nullptr,nullptr,nullptr}, nullptr};

    hipMemsetAsync(stats, 0, NSLOT*256*8 + 256 + 4096, stream);
    pack_count<<<dim3(NPTS/256),dim3(256),0,stream>>>(coords, pc, cellcnt);
    prefix1024<<<dim3(1),dim3(1024),0,stream>>>(cellcnt, cs, cptr);
    scatter_pts<<<dim3(NPTS/256),dim3(256),0,stream>>>(pc, cptr, spt);
    WPtrs wp{{W_top,W_alp,W_d2,W_g2,W_dn}};
    prep_weights<<<dim3(5*2*16384/256),dim3(256),0,stream>>>(wp, wt);
    // static weight combines: slots (1,l) <- Wphi@Wg1, (2,l) <- Wpsi@Wg1 (transposed f16 out)
    {
        CompStatic cstat{{W_phi, W_phi+16384, W_psi, W_psi+16384}};
        BTS bts{{W_g1, W_g1+16384, W_g1, W_g1+16384}, nullptr};
        gemm128<CompStatic,true,false,false,false,true,true><<<dim3(1,4),dim3(256),0,stream>>>(
            cstat, nullptr, bts, nullptr, wt+2*16384, nullptr, 0, 16384, nullptr,nullptr,nullptr);
    }
    knn_grid<<<dim3(4096),dim3(256),0,stream>>>(pc, spt, cs, idxg, rel, sM);
    finalize_d1<<<dim3(1),dim3(256),0,stream>>>(sM, W_d1, b_d1, g_d1, bt_d1, A_d1, C_d1);

    const float* fin=feats;
    for (int l=0;l<2;l++){
        const u16* wt_top=wt+(0*2+l)*16384;
        const u16* wt_d2 =wt+(4*2+l)*16384;
        const u16* wt_c  =wt+(5*2+l)*16384;   // dynamic d2_g1 combined
        const u16* wt_g2 =wt+(6*2+l)*16384;
        const u16* wt_dn =wt+(7*2+l)*16384;

        // h16 = f @ W_top (f16 out, stats fused)
        gemm128<CompF32,true,false,true,false,false,false><<<dim3(NPTS/128),dim3(256),0,stream>>>(
            CompF32{fin}, wt_top, noBT, nullptr, h16, P, 0, 0, nullptr,nullptr,nullptr);
        finalize_affine<<<dim3(1),dim3(128),0,stream>>>(P, g_top+l*128, bt_top+l*128, (double)NPTS,
            A_top, C_top, nullptr,nullptr,nullptr,nullptr);

        // q' / k' / v in ONE launch (weight slots 1,2,3 stride 2*16384)
        gemm128<CompH16Aff,true,false,false,false,false,false><<<dim3(NPTS/128,3),dim3(256),0,stream>>>(
            CompH16Aff{h16,A_top,C_top}, wt+(1*2+l)*16384, noBT, nullptr, qb, nullptr,
            2*16384, (long)NPTS*HD, nullptr,nullptr,nullptr);

        // pose2 = relu(BN1(rel@W_d1+b_d1)) @ W_d2 + b_d2 (stats fused)
        gemm128<CompPose1,true,true,true,false,false,false><<<dim3(NKROWS/128),dim3(256),0,stream>>>(
            CompPose1{rel, W_d1+l*384, b_d1+l*128, A_d1+l*128, C_d1+l*128}, wt_d2, noBT,
            b_d2+l*128, pose2, P, 0, 0, nullptr,nullptr,nullptr);
        finalize_affine<<<dim3(1),dim3(128),0,stream>>>(P, g_d2+l*128, bt_d2+l*128, (double)NKROWS,
            A_d2, C_d2, W_g1+l*16384, b_d2+l*128, b_g1+l*128, biasc);

        // dynamic combine: slot (5,l) <- W_d2 @ diag(A_d2) @ W_g1
        {
            CompStatic cd{{W_d2+l*16384, nullptr, nullptr, nullptr}};
            BTS bts{{W_g1+l*16384, nullptr, nullptr, nullptr}, A_d2};
            gemm128<CompStatic,true,false,false,false,true,true><<<dim3(1,1),dim3(256),0,stream>>>(
                cd, nullptr, bts, nullptr, (void*)wt_c, nullptr, 0, 0, nullptr,nullptr,nullptr);
        }

        // a1 = pose1 @ Wcomb + (q'[n] - k'[g]) + biasc   (stats fused, LDS-staged epilogue)
        gemm128<CompPose1,true,true,true,true,false,false><<<dim3(NKROWS/128),dim3(256),0,stream>>>(
            CompPose1{rel, W_d1+l*384, b_d1+l*128, A_d1+l*128, C_d1+l*128}, wt_c, noBT,
            biasc, abuf, P, 0, 0, qb, kpb, idxg);
        finalize_affine<<<dim3(1),dim3(128),0,stream>>>(P, g_g1+l*128, bt_g1+l*128, (double)NKROWS,
            A_g1, C_g1, nullptr,nullptr,nullptr,nullptr);

        // a2 = relu(BN(a1)) @ W_g2 + b_g2 (in-place, stats fused)
        gemm128<CompH16AffRelu,true,true,true,false,false,false><<<dim3(NKROWS/128),dim3(256),0,stream>>>(
            CompH16AffRelu{abuf,A_g1,C_g1}, wt_g2, noBT, b_g2+l*128, abuf, P, 0, 0, nullptr,nullptr,nullptr);
        finalize_affine<<<dim3(1),dim3(128),0,stream>>>(P, g_g2+l*128, bt_g2+l*128, (double)NKROWS,
            A_g2, C_g2, nullptr,nullptr,nullptr,nullptr);

        // softmax over K + aggregate (f16 y out)
        aggregate<<<dim3(NPTS/4),dim3(256),0,stream>>>(abuf, pose2, vvb, idxg, A_g2, C_g2, A_d2, C_d2, yb);

        // y @ W_down (stats fused) ; BN ; residual
        gemm128<CompH16,false,false,true,false,false,false><<<dim3(NPTS/128),dim3(256),0,stream>>>(
            CompH16{yb}, wt_dn, noBT, nullptr, ydown, P, 0, 0, nullptr,nullptr,nullptr);
        finalize_affine<<<dim3(1),dim3(128),0,stream>>>(P, g_dn+l*128, bt_dn+l*128, (double)NPTS,
            A_dn, C_dn, nullptr,nullptr,nullptr,nullptr);
        residual<<<dim3(NPTS*HD/256),dim3(256),0,stream>>>(ydown, A_dn, C_dn, fin, (l==1)?(float*)d_out:fbuf);
        fin=fbuf;
    }
}